// Round 7
// baseline (253.988 us; speedup 1.0000x reference)
//
#include <hip/hip_runtime.h>

// db4 DWT, mode='symmetric', matching the JAX reference exactly:
//   cA[k] = sum_t x[reflect(2k+t-6)] * w[t]
//   cD[k] = sum_t x[reflect(2k+t-6)] * ((t&1) ? -w[7-t] : +w[7-t])
//   reflect: g<0 -> -1-g ; g>=N -> 2N-1-g ;  K = (N+7)/2
//   outputs: cA (B,K) || cD (B,K) || x3 (B,8) passthrough
//
// R7: (a) persistent blocks (grid ~1958, 17 consecutive tiles each, grid-stride
// per Guideline 11 — R3's 33k 4-wave blocks relied on CU-slot refill for latency
// hiding); (b) row-parity output shift: odd rows pair outputs (2t-1, 2t) so the
// float2 store address row*K+k0 is even for ALL rows (K odd => row*K parity
// alternates; R3 fell back to half-density scalar stores on odd rows).
// Loads unchanged: thread t window = x[4t-8 .. 4t+3], 3 lane-consecutive
// float4s (coalesced 1KB wave transactions). x3 tail copy fused into idle
// threads of each row's last tile.

__device__ __forceinline__ constexpr float WLc(int t) {
    constexpr float w[8] = {
        0.23037781330885523f,  0.7148465705525415f,  0.6308807679295904f,
       -0.02798376941698385f, -0.18703481171888114f, 0.030841381835986965f,
        0.032883011666982945f,-0.010597401784997278f };
    return w[t];
}
__device__ __forceinline__ constexpr float WHc(int t) {
    return (t & 1) ? -WLc(7 - t) : WLc(7 - t);
}

__global__ __launch_bounds__(256) void dwt_db4_kernel(
    const float* __restrict__ x, const float* __restrict__ x3,
    float* __restrict__ out,
    int B, int N, int K, int tpr, int tiles_total, int tpb)
{
    int tile_id = blockIdx.x * tpb;
    if (tile_id >= tiles_total) return;
    int row  = tile_id / tpr;                 // one div per block
    int tile = tile_id - row * tpr;
    const int nit = min(tpb, tiles_total - tile_id);
    const long long BK = (long long)B * K;

    for (int it = 0; it < nit; ++it) {
        const int trow = (tile << 8) + (int)threadIdx.x;  // thread idx within row
        const int s    = row & 1;                         // parity shift
        const int k0   = 2 * trow - s;                    // first output (may be -1)

        if (k0 < K) {
            const float* __restrict__ xr = x + (long long)row * N;
            const int gbase = 4 * trow - 8;               // 16B-aligned window base

            float f[12];
            if (gbase >= 0 && gbase + 12 <= N) {
                // interior: 3 lane-consecutive float4 loads
                const float4* __restrict__ sp =
                    reinterpret_cast<const float4*>(xr + gbase);
                float4 v0 = sp[0], v1 = sp[1], v2 = sp[2];
                f[0]=v0.x; f[1]=v0.y; f[2]=v0.z; f[3]=v0.w;
                f[4]=v1.x; f[5]=v1.y; f[6]=v1.z; f[7]=v1.w;
                f[8]=v2.x; f[9]=v2.y; f[10]=v2.z; f[11]=v2.w;
            } else {
                // row edges: scalar gather with symmetric reflection
                #pragma unroll
                for (int m = 0; m < 12; ++m) {
                    int g = gbase + m;
                    if (g < 0) g = -1 - g;
                    if (g >= N) g = 2 * N - 1 - g;
                    f[m] = xr[g];
                }
            }

            // even rows (s=0): outputs (2t,2t+1)   use f[2..9],  f[4..11]
            // odd  rows (s=1): outputs (2t-1,2t)   use f[0..7],  f[2..9]
            const int off = 2 - 2 * s;
            float a0 = f[off]     * WLc(0), d0 = f[off]     * WHc(0);
            float a1 = f[off + 2] * WLc(0), d1 = f[off + 2] * WHc(0);
            #pragma unroll
            for (int t = 1; t < 8; ++t) {
                a0 = fmaf(f[off + t],     WLc(t), a0);
                d0 = fmaf(f[off + t],     WHc(t), d0);
                a1 = fmaf(f[off + 2 + t], WLc(t), a1);
                d1 = fmaf(f[off + 2 + t], WHc(t), d1);
            }

            const long long obase = (long long)row * K + k0;  // even when pair valid
            float* __restrict__ oA = out + obase;
            float* __restrict__ oD = oA + BK;
            const bool v0ok = (k0 >= 0);
            const bool v1ok = (k0 + 1 < K);
            if (v0ok && v1ok) {
                *reinterpret_cast<float2*>(oA) = make_float2(a0, a1);  // 8B-aligned
                *reinterpret_cast<float2*>(oD) = make_float2(d0, d1);
            } else if (!v0ok) {          // odd row, trow=0: only k=0 (second slot)
                oA[1] = a1; oD[1] = d1;
            } else {                     // k0 == K-1 (even row tail): single output
                oA[0] = a0; oD[0] = d0;
            }
        } else {
            // idle threads of the row's last tile: fused x3 passthrough
            const int j = trow - (K + 1) / 2;     // first idle trow = (K+1)/2
            if (j >= 0 && j < 8) {
                out[2 * BK + (long long)row * 8 + j] = x3[(long long)row * 8 + j];
            }
        }

        ++tile;
        if (tile == tpr) { tile = 0; ++row; }
    }
}

extern "C" void kernel_launch(void* const* d_in, const int* in_sizes, int n_in,
                              void* d_out, int out_size, void* d_ws, size_t ws_size,
                              hipStream_t stream) {
    const float* x1 = (const float*)d_in[0];
    // d_in[1] = x2: unused by the reference
    const float* x3 = (const float*)d_in[2];
    float* out = (float*)d_out;

    const int B = in_sizes[2] / 8;          // 512
    const int N = in_sizes[0] / B;          // 65536
    const int K = (N + 7) / 2;              // 32771
    const int tpr = ((K + 1) / 2 + 8 + 255) / 256;   // 65: covers outputs + 8 x3 lanes
    const int tiles_total = B * tpr;        // 33280
    const int tpb = 17;                     // tiles per block -> grid ~1958 (≈8/CU)
    const int grid = (tiles_total + tpb - 1) / tpb;

    dwt_db4_kernel<<<grid, 256, 0, stream>>>(x1, x3, out, B, N, K,
                                             tpr, tiles_total, tpb);
}

// Round 12
// 250.323 us; speedup vs baseline: 1.0146x; 1.0146x over previous
//
#include <hip/hip_runtime.h>

// db4 DWT, mode='symmetric', matching the JAX reference exactly:
//   cA[k] = sum_t x[reflect(2k+t-6)] * w[t]
//   cD[k] = sum_t x[reflect(2k+t-6)] * ((t&1) ? -w[7-t] : +w[7-t])
//   reflect: g<0 -> -1-g ; g>=N -> 2N-1-g ;  K = (N+7)/2
//   outputs: cA (B,K) || cD (B,K) || x3 (B,8) passthrough
//
// R8 (4th resubmit; broker timeouts, never benched):
// explicit 1-deep software pipeline in the persistent loop.
// R7 post-mortem: VGPR=20 proved the compiler serialized each iteration
// (load -> vmcnt(0) -> compute -> store), exposing ~1100cy HBM latency every
// tile; VALUBusy was 10.7%. Here iteration i+1's 3 float4 loads are issued
// BEFORE computing tile i from registers (rotate at loop end), so the wait
// lands after a full compute+store span. Loads are made unconditional/
// branchless via a clamped base (always in-row, always aligned); the rare
// edge lanes (2-3 per row) redo their 12-float window with scalar symmetric
// reflection inside the compute stage.
// Store layout keeps R7's row-parity shift: odd rows pair outputs (2t-1,2t)
// so the float2 store address row*K+k0 is even for ALL rows (K is odd).
// x3 passthrough fused into idle threads of each row's last tile.

__device__ __forceinline__ constexpr float WLc(int t) {
    constexpr float w[8] = {
        0.23037781330885523f,  0.7148465705525415f,  0.6308807679295904f,
       -0.02798376941698385f, -0.18703481171888114f, 0.030841381835986965f,
        0.032883011666982945f,-0.010597401784997278f };
    return w[t];
}
__device__ __forceinline__ constexpr float WHc(int t) {
    return (t & 1) ? -WLc(7 - t) : WLc(7 - t);
}

__global__ __launch_bounds__(256) void dwt_db4_kernel(
    const float* __restrict__ x, const float* __restrict__ x3,
    float* __restrict__ out,
    int B, int N, int K, int tpr, int tiles_total, int tpb)
{
    const int id0 = blockIdx.x * tpb;
    if (id0 >= tiles_total) return;
    const int nit = min(tpb, tiles_total - id0);
    const long long BK = (long long)B * K;
    const int tid = threadIdx.x;

    int row  = id0 / tpr;              // only div in the kernel
    int tile = id0 - row * tpr;

    // ---- prologue: issue first tile's loads (clamped base: branchless, legal) ----
    int trow = (tile << 8) + tid;
    int gb   = 4 * trow - 8;           // true window base (may be out of row)
    int cb   = min(max(gb, 0), N - 12);
    const float4* p = reinterpret_cast<const float4*>(x + (long long)row * N + cb);
    float4 v0 = p[0], v1 = p[1], v2 = p[2];

    for (int it = 0; it < nit; ++it) {
        // ---- next tile coords; last iter re-targets current (keeps addr legal) ----
        int nrow = row, ntile = tile + 1;
        if (ntile == tpr) { ntile = 0; ++nrow; }
        if (it == nit - 1) { nrow = row; ntile = tile; }

        // ---- issue next tile's loads NOW; waited only at rotation below ----
        const int ntrow = (ntile << 8) + tid;
        const int ngb   = 4 * ntrow - 8;
        const int ncb   = min(max(ngb, 0), N - 12);
        const float4* np = reinterpret_cast<const float4*>(x + (long long)nrow * N + ncb);
        float4 n0 = np[0], n1 = np[1], n2 = np[2];

        // ---- compute current tile from already-loaded v0..v2 ----
        const int s  = row & 1;
        const int k0 = 2 * trow - s;
        if (k0 < K) {
            float f[12];
            f[0]=v0.x; f[1]=v0.y; f[2] =v0.z; f[3] =v0.w;
            f[4]=v1.x; f[5]=v1.y; f[6] =v1.z; f[7] =v1.w;
            f[8]=v2.x; f[9]=v2.y; f[10]=v2.z; f[11]=v2.w;
            if (gb < 0 || gb > N - 12) {
                // edge lanes only (2-3 per row): scalar symmetric-reflect gather
                const float* __restrict__ xr = x + (long long)row * N;
                #pragma unroll
                for (int m = 0; m < 12; ++m) {
                    int g = gb + m;
                    if (g < 0) g = -1 - g;
                    if (g >= N) g = 2 * N - 1 - g;
                    f[m] = xr[g];
                }
            }

            // even rows (s=0): outputs (2t,2t+1) use f[2..9], f[4..11]
            // odd  rows (s=1): outputs (2t-1,2t) use f[0..7], f[2..9]
            const int off = 2 - 2 * s;
            float a0 = f[off]     * WLc(0), d0 = f[off]     * WHc(0);
            float a1 = f[off + 2] * WLc(0), d1 = f[off + 2] * WHc(0);
            #pragma unroll
            for (int t = 1; t < 8; ++t) {
                a0 = fmaf(f[off + t],     WLc(t), a0);
                d0 = fmaf(f[off + t],     WHc(t), d0);
                a1 = fmaf(f[off + 2 + t], WLc(t), a1);
                d1 = fmaf(f[off + 2 + t], WHc(t), d1);
            }

            const long long obase = (long long)row * K + k0;  // even when pair valid
            float* __restrict__ oA = out + obase;
            float* __restrict__ oD = oA + BK;
            const bool v0ok = (k0 >= 0);
            const bool v1ok = (k0 + 1 < K);
            if (v0ok && v1ok) {
                *reinterpret_cast<float2*>(oA) = make_float2(a0, a1);  // 8B-aligned
                *reinterpret_cast<float2*>(oD) = make_float2(d0, d1);
            } else if (!v0ok) {          // odd row, trow=0: only k=0 (second slot)
                oA[1] = a1; oD[1] = d1;
            } else {                     // k0 == K-1 (even row tail): single output
                oA[0] = a0; oD[0] = d0;
            }
        } else {
            // idle threads of the row's last tile: fused x3 passthrough
            const int j = trow - (K + 1) / 2;     // first idle trow = (K+1)/2
            if (j >= 0 && j < 8) {
                out[2 * BK + (long long)row * 8 + j] = x3[(long long)row * 8 + j];
            }
        }

        // ---- rotate pipeline registers / coords ----
        v0 = n0; v1 = n1; v2 = n2;
        row = nrow; tile = ntile; trow = ntrow; gb = ngb;
    }
}

extern "C" void kernel_launch(void* const* d_in, const int* in_sizes, int n_in,
                              void* d_out, int out_size, void* d_ws, size_t ws_size,
                              hipStream_t stream) {
    const float* x1 = (const float*)d_in[0];
    // d_in[1] = x2: unused by the reference
    const float* x3 = (const float*)d_in[2];
    float* out = (float*)d_out;

    const int B = in_sizes[2] / 8;          // 512
    const int N = in_sizes[0] / B;          // 65536
    const int K = (N + 7) / 2;              // 32771
    const int tpr = ((K + 1) / 2 + 8 + 255) / 256;   // 65: outputs + 8 x3 lanes
    const int tiles_total = B * tpr;        // 33280
    const int tpb = 17;                     // -> grid 1958 (~7.6 blocks/CU, all resident)
    const int grid = (tiles_total + tpb - 1) / tpb;

    dwt_db4_kernel<<<grid, 256, 0, stream>>>(x1, x3, out, B, N, K,
                                             tpr, tiles_total, tpb);
}